// Round 12
// baseline (452.331 us; speedup 1.0000x reference)
//
#include <hip/hip_runtime.h>
#include <math.h>

// Problem constants
#define BATCH 8192
#define NFEAT 256
#define NH1   100     // fc1 width (K of fc2)
#define NH2   50      // fc2 width (N of fc2)
#define KP    128     // K padded: 4 MFMA k-steps of 32
#define FPB   4       // features per block (inner loop, LDS double-buffered)
#define RPB   256     // batch rows per block (64 per wave)

typedef __attribute__((ext_vector_type(8))) _Float16 half8;   // MFMA A/B frag
typedef __attribute__((ext_vector_type(2))) _Float16 h2v;     // packed fp16 pair
typedef __attribute__((ext_vector_type(2))) __fp16   fp16x2;  // cvt_pkrtz result
typedef __attribute__((ext_vector_type(4))) float    float4v; // MFMA acc

__device__ __forceinline__ h2v pkrtz(float a, float b) {
    fp16x2 r = __builtin_amdgcn_cvt_pkrtz(a, b);
    return __builtin_bit_cast(h2v, r);
}

// ---- workspace layout (fp32 units from ws start) ----
// w2h : NFEAT*8192 f16 = 4 MB (fragment-ordered, zero-padded)
// w1h/b1h : NFEAT*KP f16 ; tkt : 32 u32 row-block tickets
#define OFF_W1H  (NFEAT * 8192 / 2)
#define OFF_B1H  (OFF_W1H + NFEAT * KP / 2)
#define OFF_TKT  (OFF_B1H + NFEAT * KP / 2)

// ---- prep: one block per feature. Coalesced weight conversion (R10 proved
// in-main conversion loses); zeroes out slice + tickets.
__global__ __launch_bounds__(256) void prep(
    const float* __restrict__ W1, const float* __restrict__ b1,
    const float* __restrict__ W2, float* __restrict__ ws,
    float* __restrict__ out)
{
    const int f = blockIdx.x;
    const int t = threadIdx.x;
    _Float16* w1h = (_Float16*)(ws + OFF_W1H) + f * KP;
    _Float16* b1h = (_Float16*)(ws + OFF_B1H) + f * KP;
    _Float16* w2h = (_Float16*)ws + (size_t)f * 8192;

    if (t < KP) {
        w1h[t] = (_Float16)((t < NH1) ? W1[f * NH1 + t] : 0.f);
        b1h[t] = (_Float16)((t < NH1) ? b1[f * NH1 + t] : 0.f);
    }
    if (t < 32) out[f * 32 + t] = 0.f;
    if (f == 0 && t < 32) ((unsigned*)(ws + OFF_TKT))[t] = 0u;

    // w2h[f][kk][nt][lane][j] = f16(W2[f][o=16*nt+(lane&15)][h=32*kk+8*(lane>>4)+j])
    const float* w2g = W2 + (size_t)f * NH2 * NH1;
#pragma unroll
    for (int i = 0; i < 32; ++i) {
        const int e    = i * 256 + t;        // 0..8191
        const int j    = e & 7;
        const int lane = (e >> 3) & 63;
        const int nt   = (e >> 9) & 3;
        const int kk   = e >> 11;
        const int o    = nt * 16 + (lane & 15);
        const int h    = kk * 32 + (lane >> 4) * 8 + j;
        w2h[e] = (_Float16)((o < NH2 && h < NH1) ? w2g[o * NH1 + h] : 0.f);
    }
}

// async 16KB feature-fragment stage: 4 x (256 lanes x 16B) direct
// global->LDS, zero VGPRs (R11's int4 prefetch spilled to scratch).
// Lane-ordered linear copy == the legal wave-uniform-base + lane*16 pattern.
__device__ __forceinline__ void stage_async(
    const _Float16* __restrict__ src, _Float16* dst, int t)
{
#pragma unroll
    for (int i = 0; i < 4; ++i) {
        const _Float16* g = src + (i * 256 + t) * 8;
        _Float16* l       = dst + (i * 256 + t) * 8;
        __builtin_amdgcn_global_load_lds(
            (const __attribute__((address_space(1))) unsigned*)g,
            (__attribute__((address_space(3))) unsigned*)l, 16, 0, 0);
    }
}

// ---- main: block = 4 waves x 256 rows, one feature at a time over FPB=4.
// B double-buffered in LDS via global_load_lds; rp accumulates across
// features (atomics /FPB); x loaded once as float4 covering all 4 features.
// Finish (bias+sigmoid) fused via per-row-block tickets: 32 counters, 64
// increments each (no single-address convoy as in R7).
__global__ __launch_bounds__(256, 3) void nam_mfma(
    const float* __restrict__ x,
    float* __restrict__ ws,
    const float* __restrict__ b2,
    const float* __restrict__ W3,
    const float* __restrict__ bias,
    float* __restrict__ out)
{
    __shared__ _Float16 lds[2][8192];      // 2 x 16 KB fragment buffers

    const int t   = threadIdx.x;
    const int wv  = t >> 6;
    const int l64 = t & 63;
    const int ln  = t & 15;
    const int qd  = (t >> 4) & 3;
    const int rowbase = blockIdx.x * RPB + wv * 64;
    const int f0      = blockIdx.y * FPB;

    const _Float16* w2h = (const _Float16*)ws;
    const _Float16* w1h = (const _Float16*)(ws + OFF_W1H);
    const _Float16* b1h = (const _Float16*)(ws + OFF_B1H);

    int osrc[4];
#pragma unroll
    for (int nt = 0; nt < 4; ++nt) {
        const int o = nt * 16 + ln;
        osrc[nt] = (o < NH2) ? o : 0;      // clamped; killed by wo=0
    }

    // x for all 4 features of this block, all 4 m-tiles: 4 float4 loads.
    float4 xq[4];
#pragma unroll
    for (int mt = 0; mt < 4; ++mt)
        xq[mt] = *(const float4*)(x + (size_t)(rowbase + mt * 16 + ln) * NFEAT + f0);

    stage_async(w2h + (size_t)f0 * 8192, lds[0], t);
    __syncthreads();

    float rp[4][4] = {{0.f}, {0.f}, {0.f}, {0.f}};   // contrib, summed over f

#pragma unroll
    for (int fi = 0; fi < FPB; ++fi) {
        const int f = f0 + fi;
        const _Float16* B = lds[fi & 1];

        // kick off next feature's staging; completes at this iter's barrier
        if (fi + 1 < FPB)
            stage_async(w2h + (size_t)(f + 1) * 8192, lds[(fi + 1) & 1], t);

        const float xf[4] = {xq[0][fi], xq[1][fi], xq[2][fi], xq[3][fi]};
        h2v xh[4];
#pragma unroll
        for (int mt = 0; mt < 4; ++mt) xh[mt] = pkrtz(xf[mt], xf[mt]);

        float4v acc[4][4];
#pragma unroll
        for (int mt = 0; mt < 4; ++mt)
#pragma unroll
            for (int nt = 0; nt < 4; ++nt) acc[mt][nt] = (float4v){0.f, 0.f, 0.f, 0.f};

        const h2v* wp = (const h2v*)(w1h + f * KP);
        const h2v* cp = (const h2v*)(b1h + f * KP);
        const h2v z2 = (h2v){(_Float16)0.f, (_Float16)0.f};

#pragma unroll
        for (int kk = 0; kk < 4; ++kk) {
            half8 bf[4];
#pragma unroll
            for (int nt = 0; nt < 4; ++nt)
                bf[nt] = *(const half8*)(B + (kk * 4 + nt) * 512 + l64 * 8);

            const int pb = kk * 16 + qd * 4;       // h2v pair index
            const h2v w0 = wp[pb], w1 = wp[pb + 1], w2 = wp[pb + 2], w3 = wp[pb + 3];
            const h2v c0 = cp[pb], c1 = cp[pb + 1], c2 = cp[pb + 2], c3 = cp[pb + 3];

#pragma unroll
            for (int mt = 0; mt < 4; ++mt) {
                half8 af;
                h2v* ap = (h2v*)&af;
                ap[0] = __builtin_elementwise_max(w0 * xh[mt] + c0, z2);
                ap[1] = __builtin_elementwise_max(w1 * xh[mt] + c1, z2);
                ap[2] = __builtin_elementwise_max(w2 * xh[mt] + c2, z2);
                ap[3] = __builtin_elementwise_max(w3 * xh[mt] + c3, z2);
#pragma unroll
                for (int nt = 0; nt < 4; ++nt)
                    acc[mt][nt] = __builtin_amdgcn_mfma_f32_16x16x32_f16(
                        af, bf[nt], acc[mt][nt], 0, 0, 0);
            }
        }

        // epilogue for this f: h2 = relu(acc + b2); rp += h2 * w3
        const float* __restrict__ b2g = b2 + f * NH2;
        const float* __restrict__ w3g = W3 + f * NH2;
#pragma unroll
        for (int nt = 0; nt < 4; ++nt) {
            const int o = nt * 16 + ln;
            const float bo = b2g[osrc[nt]];
            const float wo = (o < NH2) ? w3g[osrc[nt]] : 0.f;
#pragma unroll
            for (int mt = 0; mt < 4; ++mt)
#pragma unroll
                for (int r = 0; r < 4; ++r)
                    rp[mt][r] = fmaf(fmaxf(acc[mt][nt][r] + bo, 0.f), wo, rp[mt][r]);
        }

        __syncthreads();   // drains staging (vmcnt) + releases buffer fi&1
    }

    // ---- shuffle-reduce rp over the 16 columns, one atomic per row ----
#pragma unroll
    for (int mt = 0; mt < 4; ++mt)
#pragma unroll
        for (int r = 0; r < 4; ++r) {
            float v = rp[mt][r];
            v += __shfl_xor(v, 1);
            v += __shfl_xor(v, 2);
            v += __shfl_xor(v, 4);
            v += __shfl_xor(v, 8);
            if (ln == 0)
                atomicAdd(out + rowbase + mt * 16 + qd * 4 + r, v);
        }

    // ---- fused finish: per-row-block ticket (32 counters x 64 blocks) ----
    __shared__ unsigned last;
    __threadfence();                 // our atomics visible device-wide
    __syncthreads();                 // all 4 waves' atomics issued+fenced
    if (t == 0) {
        unsigned* tkt = (unsigned*)(ws + OFF_TKT) + blockIdx.x;
        last = atomicAdd(tkt, 1u);
    }
    __syncthreads();
    if (last == (unsigned)(gridDim.y - 1)) {
        const float bb = bias[0];
        const int b = blockIdx.x * RPB + t;              // 256 rows, 256 thr
        const float v = atomicAdd(out + b, 0.0f) + bb;   // coherent read
        out[b] = 1.0f / (1.0f + expf(-v));
    }
}

extern "C" void kernel_launch(void* const* d_in, const int* in_sizes, int n_in,
                              void* d_out, int out_size, void* d_ws, size_t ws_size,
                              hipStream_t stream) {
    const float* x    = (const float*)d_in[0];
    const float* W1   = (const float*)d_in[1];
    const float* b1   = (const float*)d_in[2];
    const float* W2   = (const float*)d_in[3];
    const float* b2   = (const float*)d_in[4];
    const float* W3   = (const float*)d_in[5];
    const float* bias = (const float*)d_in[6];
    float* out = (float*)d_out;
    float* ws  = (float*)d_ws;   // ~4.3 MB used

    prep<<<NFEAT, 256, 0, stream>>>(W1, b1, W2, ws, out);

    nam_mfma<<<dim3(BATCH / RPB, NFEAT / FPB), 256, 0, stream>>>(
        x, ws, b2, W3, bias, out);
}

// Round 13
// 130.966 us; speedup vs baseline: 3.4538x; 3.4538x over previous
//
#include <hip/hip_runtime.h>
#include <math.h>

// Problem constants
#define BATCH 8192
#define NFEAT 256
#define NH1   100     // fc1 width (K of fc2)
#define NH2   50      // fc2 width (N of fc2)
#define KP    128     // K padded: 4 MFMA k-steps of 32
#define FPB   8       // features per block (inner loop)
#define RPB   256     // batch rows per block (64 per wave)

typedef __attribute__((ext_vector_type(8))) _Float16 half8;   // MFMA A/B frag
typedef __attribute__((ext_vector_type(2))) _Float16 h2v;     // packed fp16 pair
typedef __attribute__((ext_vector_type(2))) __fp16   fp16x2;  // cvt_pkrtz result
typedef __attribute__((ext_vector_type(4))) float    float4v; // MFMA acc

__device__ __forceinline__ h2v pkrtz(float a, float b) {
    fp16x2 r = __builtin_amdgcn_cvt_pkrtz(a, b);
    return __builtin_bit_cast(h2v, r);
}

// ---- workspace layout (fp32 units from ws start) ----
// w2h : NFEAT*8192 f16 = 4 MB (fragment-ordered, zero-padded)
// w1h/b1h : NFEAT*KP f16 (zero-padded)
#define OFF_W1H  (NFEAT * 8192 / 2)
#define OFF_B1H  (OFF_W1H + NFEAT * KP / 2)

// ---- prep: one block per feature. Coalesced weight conversion; zeroes
// this feature's slice of out (replaces a memset node).
__global__ __launch_bounds__(256) void prep(
    const float* __restrict__ W1, const float* __restrict__ b1,
    const float* __restrict__ W2, float* __restrict__ ws,
    float* __restrict__ out)
{
    const int f = blockIdx.x;
    const int t = threadIdx.x;
    _Float16* w1h = (_Float16*)(ws + OFF_W1H) + f * KP;
    _Float16* b1h = (_Float16*)(ws + OFF_B1H) + f * KP;
    _Float16* w2h = (_Float16*)ws + (size_t)f * 8192;

    if (t < KP) {
        w1h[t] = (_Float16)((t < NH1) ? W1[f * NH1 + t] : 0.f);
        b1h[t] = (_Float16)((t < NH1) ? b1[f * NH1 + t] : 0.f);
    }
    if (t < 32) out[f * 32 + t] = 0.f;

    // w2h[f][kk][nt][lane][j] = f16(W2[f][o=16*nt+(lane&15)][h=32*kk+8*(lane>>4)+j])
    const float* w2g = W2 + (size_t)f * NH2 * NH1;
#pragma unroll
    for (int i = 0; i < 32; ++i) {
        const int e    = i * 256 + t;        // 0..8191
        const int j    = e & 7;
        const int lane = (e >> 3) & 63;
        const int nt   = (e >> 9) & 3;
        const int kk   = e >> 11;
        const int o    = nt * 16 + (lane & 15);
        const int h    = kk * 32 + (lane >> 4) * 8 + j;
        w2h[e] = (_Float16)((o < NH2 && h < NH1) ? w2g[o * NH1 + h] : 0.f);
    }
}

// ---- main: block = 4 waves x 256 rows, one feature at a time over FPB=8.
// SINGLE 16KB LDS buffer, staged per-feature with plain int4 global->LDS
// copies between two barriers: ZERO persistent staging registers (R11's
// register prefetch and R12's unrolled state both spilled to scratch -> 75
// and 280 MB of WRITE_SIZE). Live state = acc(AGPR) + rp only. rp
// accumulates across the 8 features -> 1 atomic per row per block.
__global__ __launch_bounds__(256, 3) void nam_mfma(
    const float* __restrict__ x,
    const float* __restrict__ ws,
    const float* __restrict__ b2,
    const float* __restrict__ W3,
    float* __restrict__ out)
{
    __shared__ _Float16 Bsh[8192];         // one 16 KB fragment buffer

    const int t   = threadIdx.x;
    const int wv  = t >> 6;
    const int l64 = t & 63;
    const int ln  = t & 15;
    const int qd  = (t >> 4) & 3;
    const int rowbase = blockIdx.x * RPB + wv * 64;
    const int f0      = blockIdx.y * FPB;

    const _Float16* w2h = (const _Float16*)ws;
    const _Float16* w1h = (const _Float16*)(ws + OFF_W1H);
    const _Float16* b1h = (const _Float16*)(ws + OFF_B1H);

    int osrc[4];
#pragma unroll
    for (int nt = 0; nt < 4; ++nt) {
        const int o = nt * 16 + ln;
        osrc[nt] = (o < NH2) ? o : 0;      // clamped; killed by wo=0
    }

    float rp[4][4] = {{0.f}, {0.f}, {0.f}, {0.f}};   // contrib, summed over f

#pragma unroll 1
    for (int fi = 0; fi < FPB; ++fi) {
        const int f = f0 + fi;

        // ---- stage this feature's fragments: 4 x int4 per thread ----
        if (fi > 0) __syncthreads();       // release buffer from previous f
        {
            const int4* src = (const int4*)(w2h + (size_t)f * 8192);
            int4* dst = (int4*)Bsh;
#pragma unroll
            for (int i = 0; i < 4; ++i) dst[i * 256 + t] = src[i * 256 + t];
        }
        __syncthreads();

        // x for this feature (same 64B line across fi -> L1-hot)
        h2v xh[4];
#pragma unroll
        for (int mt = 0; mt < 4; ++mt) {
            const float xs = x[(size_t)(rowbase + mt * 16 + ln) * NFEAT + f];
            xh[mt] = pkrtz(xs, xs);
        }

        float4v acc[4][4];
#pragma unroll
        for (int mt = 0; mt < 4; ++mt)
#pragma unroll
            for (int nt = 0; nt < 4; ++nt) acc[mt][nt] = (float4v){0.f, 0.f, 0.f, 0.f};

        const h2v* wp = (const h2v*)(w1h + f * KP);
        const h2v* cp = (const h2v*)(b1h + f * KP);
        const h2v z2 = (h2v){(_Float16)0.f, (_Float16)0.f};

#pragma unroll
        for (int kk = 0; kk < 4; ++kk) {
            half8 bf[4];
#pragma unroll
            for (int nt = 0; nt < 4; ++nt)
                bf[nt] = *(const half8*)(Bsh + (kk * 4 + nt) * 512 + l64 * 8);

            const int pb = kk * 16 + qd * 4;       // h2v pair index
            const h2v w0 = wp[pb], w1 = wp[pb + 1], w2 = wp[pb + 2], w3 = wp[pb + 3];
            const h2v c0 = cp[pb], c1 = cp[pb + 1], c2 = cp[pb + 2], c3 = cp[pb + 3];

#pragma unroll
            for (int mt = 0; mt < 4; ++mt) {
                half8 af;
                h2v* ap = (h2v*)&af;
                ap[0] = __builtin_elementwise_max(w0 * xh[mt] + c0, z2);
                ap[1] = __builtin_elementwise_max(w1 * xh[mt] + c1, z2);
                ap[2] = __builtin_elementwise_max(w2 * xh[mt] + c2, z2);
                ap[3] = __builtin_elementwise_max(w3 * xh[mt] + c3, z2);
#pragma unroll
                for (int nt = 0; nt < 4; ++nt)
                    acc[mt][nt] = __builtin_amdgcn_mfma_f32_16x16x32_f16(
                        af, bf[nt], acc[mt][nt], 0, 0, 0);
            }
        }

        // epilogue for this f: h2 = relu(acc + b2); rp += h2 * w3
        const float* __restrict__ b2g = b2 + f * NH2;
        const float* __restrict__ w3g = W3 + f * NH2;
#pragma unroll
        for (int nt = 0; nt < 4; ++nt) {
            const int o = nt * 16 + ln;
            const float bo = b2g[osrc[nt]];
            const float wo = (o < NH2) ? w3g[osrc[nt]] : 0.f;
#pragma unroll
            for (int mt = 0; mt < 4; ++mt)
#pragma unroll
                for (int r = 0; r < 4; ++r)
                    rp[mt][r] = fmaf(fmaxf(acc[mt][nt][r] + bo, 0.f), wo, rp[mt][r]);
        }
    }

    // ---- shuffle-reduce rp over the 16 columns, one atomic per row ----
#pragma unroll
    for (int mt = 0; mt < 4; ++mt)
#pragma unroll
        for (int r = 0; r < 4; ++r) {
            float v = rp[mt][r];
            v += __shfl_xor(v, 1);
            v += __shfl_xor(v, 2);
            v += __shfl_xor(v, 4);
            v += __shfl_xor(v, 8);
            if (ln == 0)
                atomicAdd(out + rowbase + mt * 16 + qd * 4 + r, v);
        }
}

__global__ __launch_bounds__(256) void nam_finish(
    float* __restrict__ out, const float* __restrict__ bias)
{
    const int b = blockIdx.x * blockDim.x + threadIdx.x;
    out[b] = 1.0f / (1.0f + expf(-(out[b] + bias[0])));
}

extern "C" void kernel_launch(void* const* d_in, const int* in_sizes, int n_in,
                              void* d_out, int out_size, void* d_ws, size_t ws_size,
                              hipStream_t stream) {
    const float* x    = (const float*)d_in[0];
    const float* W1   = (const float*)d_in[1];
    const float* b1   = (const float*)d_in[2];
    const float* W2   = (const float*)d_in[3];
    const float* b2   = (const float*)d_in[4];
    const float* W3   = (const float*)d_in[5];
    const float* bias = (const float*)d_in[6];
    float* out = (float*)d_out;
    float* ws  = (float*)d_ws;   // ~4.3 MB used

    prep<<<NFEAT, 256, 0, stream>>>(W1, b1, W2, ws, out);

    nam_mfma<<<dim3(BATCH / RPB, NFEAT / FPB), 256, 0, stream>>>(
        x, ws, b2, W3, out);

    nam_finish<<<BATCH / 256, 256, 0, stream>>>(out, bias);
}